// Round 1
// 425.834 us; speedup vs baseline: 1.0090x; 1.0090x over previous
//
#include <hip/hip_runtime.h>
#include <math.h>

// Problem: T=4, B=2, L=2048, D=4096, fp32.
// out_t = silu(cumsum_t(x)) - silu(cumsum_{t-1}(x)); columns over (b,l,d) independent.
// Pure streaming kernel: 256 MiB in + 256 MiB out, HBM-bound. Floor = 537MB/6.3TB/s ~ 85us.
// R1: hoisted loads, nontemporal, v_rcp_f32 (~3.4 TB/s).
// R2 (this): grid-stride persistent kernel (2048 blocks = 8/CU), depth-1 software
// prefetch: next iteration's 4 loads issue BEFORE current iteration's silu chain,
// so each wave keeps memory ops in flight continuously instead of one-shot
// load->stall->compute->store->exit. Target >= 4.7 TB/s kernel BW.

#define T_STEPS 4

typedef float v4f __attribute__((ext_vector_type(4)));

__device__ __forceinline__ v4f silu4(v4f X) {
    v4f r;
    // silu(x) = x / (1 + exp(-x)); __expf -> v_exp_f32, rcpf -> v_rcp_f32
    r.x = X.x * __builtin_amdgcn_rcpf(1.0f + __expf(-X.x));
    r.y = X.y * __builtin_amdgcn_rcpf(1.0f + __expf(-X.y));
    r.z = X.z * __builtin_amdgcn_rcpf(1.0f + __expf(-X.z));
    r.w = X.w * __builtin_amdgcn_rcpf(1.0f + __expf(-X.w));
    return r;
}

__global__ __launch_bounds__(256) void ActSWL_kernel(const v4f* __restrict__ xv,
                                                     v4f* __restrict__ ov,
                                                     unsigned n_vec) {  // (B*L*D)/4
    const unsigned stride = gridDim.x * 256u;
    unsigned idx = blockIdx.x * 256u + threadIdx.x;
    if (idx >= n_vec) return;

    const unsigned n1 = n_vec, n2 = 2u * n_vec, n3 = 3u * n_vec;

    // Prologue: loads for iteration 0.
    v4f a0 = __builtin_nontemporal_load(xv + idx);
    v4f a1 = __builtin_nontemporal_load(xv + idx + n1);
    v4f a2 = __builtin_nontemporal_load(xv + idx + n2);
    v4f a3 = __builtin_nontemporal_load(xv + idx + n3);

    for (;;) {
        const unsigned nxt = idx + stride;
        const bool more = nxt < n_vec;

        // Prefetch next iteration's 4 loads BEFORE the transcendental chain:
        // ~400 cycles of silu compute hides their latency.
        v4f b0, b1, b2, b3;
        if (more) {
            b0 = __builtin_nontemporal_load(xv + nxt);
            b1 = __builtin_nontemporal_load(xv + nxt + n1);
            b2 = __builtin_nontemporal_load(xv + nxt + n2);
            b3 = __builtin_nontemporal_load(xv + nxt + n3);
        }

        v4f X  = a0;
        v4f y0 = silu4(X);
        X += a1;
        v4f y1 = silu4(X);
        X += a2;
        v4f y2 = silu4(X);
        X += a3;
        v4f y3 = silu4(X);

        __builtin_nontemporal_store(y0,      ov + idx);
        __builtin_nontemporal_store(y1 - y0, ov + idx + n1);
        __builtin_nontemporal_store(y2 - y1, ov + idx + n2);
        __builtin_nontemporal_store(y3 - y2, ov + idx + n3);

        if (!more) break;
        a0 = b0; a1 = b1; a2 = b2; a3 = b3;
        idx = nxt;
    }
}

extern "C" void kernel_launch(void* const* d_in, const int* in_sizes, int n_in,
                              void* d_out, int out_size, void* d_ws, size_t ws_size,
                              hipStream_t stream) {
    const v4f* xv = (const v4f*)d_in[0];
    v4f* ov       = (v4f*)d_out;

    const long long n_total = (long long)in_sizes[0];   // T*B*L*D = 67,108,864
    const unsigned n_vec    = (unsigned)(n_total / T_STEPS / 4);  // 4,194,304 float4s

    const int block = 256;
    // Grid-stride: 2048 blocks = 8 blocks/CU on 256 CUs -> 32 waves/CU, 8 iters/thread.
    unsigned grid = (n_vec + block - 1) / block;
    if (grid > 2048u) grid = 2048u;

    ActSWL_kernel<<<dim3(grid), dim3(block), 0, stream>>>(xv, ov, n_vec);
}